// Round 1
// baseline (698.893 us; speedup 1.0000x reference)
//
#include <hip/hip_runtime.h>
#include <hip/hip_bf16.h>

#define B 8
#define CIN 12
#define CQ 36
#define N 4096
#define SCALE 0.28867513459481287f   // 1/sqrt(12)
#define NSPLIT 8
#define CHUNK (N / NSPLIT)           // 512
#define TILE 32

#define QKV_SZ (B * CQ * N)          // 1179648 floats
#define PSUM_SZ (NSPLIT * B * N)     // 262144
#define RINV_SZ (B * N)              // 32768
// pattn: NSPLIT * B * CQ * N = 9437184 floats

// ---------------- QKV projection: q,k,v = W @ x + b (k pre-scaled) ---------
__global__ __launch_bounds__(256) void qkv_kernel(
    const float* __restrict__ x,
    const float* __restrict__ wq, const float* __restrict__ bq,
    const float* __restrict__ wk, const float* __restrict__ bk,
    const float* __restrict__ wv, const float* __restrict__ bv,
    float* __restrict__ q, float* __restrict__ k, float* __restrict__ v) {
  __shared__ float sw[3 * CQ * CIN + 3 * CQ];
  float* swq = sw;
  float* swk = sw + CQ * CIN;
  float* swv = sw + 2 * CQ * CIN;
  float* sb  = sw + 3 * CQ * CIN;
  int tid = threadIdx.x;
  for (int e = tid; e < CQ * CIN; e += 256) {
    swq[e] = wq[e]; swk[e] = wk[e]; swv[e] = wv[e];
  }
  if (tid < CQ) { sb[tid] = bq[tid]; sb[CQ + tid] = bk[tid]; sb[2 * CQ + tid] = bv[tid]; }
  __syncthreads();
  int gid = blockIdx.x * 256 + tid;      // over B*N
  int b = gid >> 12;
  int n = gid & (N - 1);
  float xv[CIN];
#pragma unroll
  for (int i = 0; i < CIN; ++i) xv[i] = x[(b * CIN + i) * N + n];
  const int base = b * CQ * N + n;
#pragma unroll
  for (int o = 0; o < CQ; ++o) {
    float aq = sb[o], ak = sb[CQ + o], av = sb[2 * CQ + o];
#pragma unroll
    for (int i = 0; i < CIN; ++i) {
      float xi = xv[i];
      aq += swq[o * CIN + i] * xi;
      ak += swk[o * CIN + i] * xi;
      av += swv[o * CIN + i] * xi;
    }
    q[base + o * N] = aq;
    k[base + o * N] = ak * SCALE;   // fold softmax scale into k
    v[base + o * N] = av;
  }
}

// ---------------- Pass 1: rowsum_n = sum_m exp(s[n,m]) ---------------------
__global__ __launch_bounds__(256) void stats_kernel(
    const float* __restrict__ q, const float* __restrict__ k,
    float* __restrict__ psum) {
  __shared__ float qs[TILE * CQ];   // [j][c], rows 16B-aligned (36*4B = 144B)
  int tid = threadIdx.x;
  int b = blockIdx.y, z = blockIdx.z;
  int n = blockIdx.x * 256 + tid;
  const float* qb = q + b * CQ * N;
  const float* kb = k + b * CQ * N;
  float kc[CQ];
#pragma unroll
  for (int c = 0; c < CQ; ++c) kc[c] = kb[c * N + n];
  float sum = 0.f;
  int m0base = z * CHUNK;
  for (int t = 0; t < CHUNK; t += TILE) {
    int m0 = m0base + t;
    __syncthreads();
    for (int e = tid; e < TILE * CQ; e += 256) {
      int c = e >> 5;           // e / TILE
      int j = e & (TILE - 1);
      qs[j * CQ + c] = qb[c * N + m0 + j];   // coalesced over j
    }
    __syncthreads();
#pragma unroll 2
    for (int j = 0; j < TILE; ++j) {
      const float4* qj = (const float4*)(&qs[j * CQ]);
      float s0 = 0.f, s1 = 0.f, s2 = 0.f, s3 = 0.f;
#pragma unroll
      for (int cc = 0; cc < CQ / 4; ++cc) {
        float4 t4 = qj[cc];
        s0 += kc[4 * cc + 0] * t4.x;
        s1 += kc[4 * cc + 1] * t4.y;
        s2 += kc[4 * cc + 2] * t4.z;
        s3 += kc[4 * cc + 3] * t4.w;
      }
      sum += __expf((s0 + s1) + (s2 + s3));
    }
  }
  psum[(z * B + b) * N + n] = sum;
}

// ---------------- combine partial rowsums -> 1/rowsum ----------------------
__global__ __launch_bounds__(256) void combine_kernel(
    const float* __restrict__ psum, float* __restrict__ rinv) {
  int gid = blockIdx.x * 256 + threadIdx.x;   // over B*N
  float s = 0.f;
#pragma unroll
  for (int z = 0; z < NSPLIT; ++z) s += psum[z * B * N + gid];
  rinv[gid] = 1.0f / s;
}

// ---------------- Pass 2: attn[c,m] += (v'[c,n]) * exp(s[n,m]) -------------
__global__ __launch_bounds__(256) void attn_kernel(
    const float* __restrict__ q, const float* __restrict__ k,
    const float* __restrict__ v, const float* __restrict__ rinv,
    float* __restrict__ pattn) {
  __shared__ float ks[TILE * CQ];
  __shared__ float vs[TILE * CQ];
  int tid = threadIdx.x;
  int b = blockIdx.y, z = blockIdx.z;
  int m = blockIdx.x * 256 + tid;
  const float* qb = q + b * CQ * N;
  const float* kb = k + b * CQ * N;
  const float* vb = v + b * CQ * N;
  const float* rb = rinv + b * N;
  float qc[CQ];
#pragma unroll
  for (int c = 0; c < CQ; ++c) qc[c] = qb[c * N + m];
  float acc[CQ];
#pragma unroll
  for (int c = 0; c < CQ; ++c) acc[c] = 0.f;
  int n0base = z * CHUNK;
  for (int t = 0; t < CHUNK; t += TILE) {
    int n0 = n0base + t;
    __syncthreads();
    for (int e = tid; e < TILE * CQ; e += 256) {
      int c = e >> 5;
      int j = e & (TILE - 1);
      int n = n0 + j;
      ks[j * CQ + c] = kb[c * N + n];
      vs[j * CQ + c] = vb[c * N + n] * rb[n];   // fold 1/rowsum into v
    }
    __syncthreads();
    for (int j = 0; j < TILE; ++j) {
      const float4* kj = (const float4*)(&ks[j * CQ]);
      float s0 = 0.f, s1 = 0.f, s2 = 0.f, s3 = 0.f;
#pragma unroll
      for (int cc = 0; cc < CQ / 4; ++cc) {
        float4 t4 = kj[cc];
        s0 += qc[4 * cc + 0] * t4.x;
        s1 += qc[4 * cc + 1] * t4.y;
        s2 += qc[4 * cc + 2] * t4.z;
        s3 += qc[4 * cc + 3] * t4.w;
      }
      float p = __expf((s0 + s1) + (s2 + s3));
      const float4* vj = (const float4*)(&vs[j * CQ]);
#pragma unroll
      for (int cc = 0; cc < CQ / 4; ++cc) {
        float4 t4 = vj[cc];
        acc[4 * cc + 0] += t4.x * p;
        acc[4 * cc + 1] += t4.y * p;
        acc[4 * cc + 2] += t4.z * p;
        acc[4 * cc + 3] += t4.w * p;
      }
    }
  }
  float* pa = pattn + ((size_t)(z * B + b) * CQ) * N + m;
#pragma unroll
  for (int c = 0; c < CQ; ++c) pa[c * N] = acc[c];
}

// ---------------- sum n-splits + output projection -------------------------
__global__ __launch_bounds__(256) void out_kernel(
    const float* __restrict__ pattn,
    const float* __restrict__ wo, const float* __restrict__ bo,
    float* __restrict__ out) {
  __shared__ float swo[CIN * CQ];
  __shared__ float sbo[CIN];
  int tid = threadIdx.x;
  for (int e = tid; e < CIN * CQ; e += 256) swo[e] = wo[e];
  if (tid < CIN) sbo[tid] = bo[tid];
  __syncthreads();
  int gid = blockIdx.x * 256 + tid;   // over B*N
  int b = gid >> 12;
  int m = gid & (N - 1);
  float at[CQ];
#pragma unroll
  for (int c = 0; c < CQ; ++c) {
    float s = 0.f;
#pragma unroll
    for (int z = 0; z < NSPLIT; ++z)
      s += pattn[((size_t)(z * B + b) * CQ + c) * N + m];
    at[c] = s;
  }
#pragma unroll
  for (int i = 0; i < CIN; ++i) {
    float o = sbo[i];
#pragma unroll
    for (int c = 0; c < CQ; ++c) o += swo[i * CQ + c] * at[c];
    out[(b * CIN + i) * N + m] = o;
  }
}

extern "C" void kernel_launch(void* const* d_in, const int* in_sizes, int n_in,
                              void* d_out, int out_size, void* d_ws, size_t ws_size,
                              hipStream_t stream) {
  const float* x  = (const float*)d_in[0];
  const float* wq = (const float*)d_in[1];
  const float* bq = (const float*)d_in[2];
  const float* wk = (const float*)d_in[3];
  const float* bk = (const float*)d_in[4];
  const float* wv = (const float*)d_in[5];
  const float* bv = (const float*)d_in[6];
  const float* wo = (const float*)d_in[7];
  const float* bo = (const float*)d_in[8];
  float* out = (float*)d_out;

  float* ws   = (float*)d_ws;
  float* q    = ws;
  float* k    = q + QKV_SZ;
  float* v    = k + QKV_SZ;
  float* psum = v + QKV_SZ;
  float* rinv = psum + PSUM_SZ;
  float* pattn = rinv + RINV_SZ;   // needs ~51 MB total ws

  qkv_kernel<<<B * N / 256, 256, 0, stream>>>(x, wq, bq, wk, bk, wv, bv, q, k, v);
  dim3 g2(N / 256, B, NSPLIT);
  stats_kernel<<<g2, 256, 0, stream>>>(q, k, psum);
  combine_kernel<<<B * N / 256, 256, 0, stream>>>(psum, rinv);
  attn_kernel<<<g2, 256, 0, stream>>>(q, k, v, rinv, pattn);
  out_kernel<<<B * N / 256, 256, 0, stream>>>(pattn, wo, bo, out);
}

// Round 2
// 224.143 us; speedup vs baseline: 3.1181x; 3.1181x over previous
//
#include <hip/hip_runtime.h>
#include <hip/hip_bf16.h>

#define B 8
#define CIN 12
#define CQ 36
#define CP 48               // channel dim padded for MFMA K (3x16)
#define N 4096
#define SCALE 0.28867513459481287f   // 1/sqrt(12)
#define ZSPLIT 4
#define NCHUNK (N / ZSPLIT) // 1024

typedef __attribute__((ext_vector_type(8)))  short bf8_t;   // 8 bf16 = 4 VGPRs
typedef __attribute__((ext_vector_type(16))) float f32x16;
typedef __attribute__((ext_vector_type(4)))  float f32x4;

__device__ __forceinline__ unsigned short f2bf(float x) {
  unsigned int u = __float_as_uint(x);
  u += 0x7FFFu + ((u >> 16) & 1u);   // round-to-nearest-even
  return (unsigned short)(u >> 16);
}

// ---------------- QKV projection -> qT/kT bf16 [b][n][CP], v fp32 ----------
__global__ __launch_bounds__(256) void qkv_kernel(
    const float* __restrict__ x,
    const float* __restrict__ wq, const float* __restrict__ bq,
    const float* __restrict__ wk, const float* __restrict__ bk,
    const float* __restrict__ wv, const float* __restrict__ bv,
    unsigned short* __restrict__ qT, unsigned short* __restrict__ kT,
    float* __restrict__ v) {
  __shared__ float sw[3 * CQ * CIN + 3 * CQ];
  float* swq = sw;
  float* swk = sw + CQ * CIN;
  float* swv = sw + 2 * CQ * CIN;
  float* sb  = sw + 3 * CQ * CIN;
  int tid = threadIdx.x;
  for (int e = tid; e < CQ * CIN; e += 256) {
    swq[e] = wq[e]; swk[e] = wk[e]; swv[e] = wv[e];
  }
  if (tid < CQ) { sb[tid] = bq[tid]; sb[CQ + tid] = bk[tid]; sb[2 * CQ + tid] = bv[tid]; }
  __syncthreads();
  int gid = blockIdx.x * 256 + tid;    // over B*N
  int b = gid >> 12;
  int n = gid & (N - 1);
  float xv[CIN];
#pragma unroll
  for (int i = 0; i < CIN; ++i) xv[i] = x[(b * CIN + i) * N + n];
  __attribute__((aligned(16))) unsigned short qrow[CP];
  __attribute__((aligned(16))) unsigned short krow[CP];
#pragma unroll
  for (int o = 0; o < CQ; ++o) {
    float aq = sb[o], ak = sb[CQ + o], av = sb[2 * CQ + o];
#pragma unroll
    for (int i = 0; i < CIN; ++i) {
      float xi = xv[i];
      aq += swq[o * CIN + i] * xi;
      ak += swk[o * CIN + i] * xi;
      av += swv[o * CIN + i] * xi;
    }
    qrow[o] = f2bf(aq);
    krow[o] = f2bf(ak * SCALE);
    v[((size_t)b * CQ + o) * N + n] = av;
  }
#pragma unroll
  for (int o = CQ; o < CP; ++o) { qrow[o] = 0; krow[o] = 0; }
  size_t rbase = ((size_t)b * N + n) * CP;
#pragma unroll
  for (int i = 0; i < 6; ++i) {
    *(uint4*)(qT + rbase + 8 * i) = *(const uint4*)&qrow[8 * i];
    *(uint4*)(kT + rbase + 8 * i) = *(const uint4*)&krow[8 * i];
  }
}

// ---------------- Pass 1: rowsum[b][n] = sum_m exp(s[n,m]) via MFMA --------
__global__ __launch_bounds__(256) void stats_kernel(
    const unsigned short* __restrict__ qT, const unsigned short* __restrict__ kT,
    float* __restrict__ rowsum) {
  __shared__ float red[4][32];
  int tid = threadIdx.x, lane = tid & 63, wave = tid >> 6;
  int b = blockIdx.y, nblk = blockIdx.x;
  int l31 = lane & 31, h = lane >> 5;
  // A frags (K tile, loop-invariant): A[n=l31][c = 8h+i + 16*mf]
  const unsigned short* krow = kT + ((size_t)b * N + nblk * 32 + l31) * CP + h * 8;
  bf8_t a0 = *(const bf8_t*)(krow);
  bf8_t a1 = *(const bf8_t*)(krow + 16);
  bf8_t a2 = *(const bf8_t*)(krow + 32);
  float rs[16];
#pragma unroll
  for (int r = 0; r < 16; ++r) rs[r] = 0.f;
  const unsigned short* qbase = qT + ((size_t)b * N + wave * (N / 4) + l31) * CP + h * 8;
  for (int t = 0; t < (N / 4) / 32; ++t) {
    const unsigned short* qrow2 = qbase + (size_t)t * 32 * CP;
    bf8_t b0 = *(const bf8_t*)(qrow2);
    bf8_t b1 = *(const bf8_t*)(qrow2 + 16);
    bf8_t b2 = *(const bf8_t*)(qrow2 + 32);
    f32x16 S;
#pragma unroll
    for (int r = 0; r < 16; ++r) S[r] = 0.f;
    S = __builtin_amdgcn_mfma_f32_32x32x16_bf16(a0, b0, S, 0, 0, 0);
    S = __builtin_amdgcn_mfma_f32_32x32x16_bf16(a1, b1, S, 0, 0, 0);
    S = __builtin_amdgcn_mfma_f32_32x32x16_bf16(a2, b2, S, 0, 0, 0);
#pragma unroll
    for (int r = 0; r < 16; ++r) rs[r] += __expf(S[r]);
  }
  // reduce over the 32 lanes (cols m) within each half-wave
#pragma unroll
  for (int off = 16; off >= 1; off >>= 1)
#pragma unroll
    for (int r = 0; r < 16; ++r) rs[r] += __shfl_xor(rs[r], off, 32);
  if (l31 == 0) {
#pragma unroll
    for (int r = 0; r < 16; ++r) {
      int row = (r & 3) + 8 * (r >> 2) + 4 * h;   // C/D row map (m74/m101)
      red[wave][row] = rs[r];
    }
  }
  __syncthreads();
  if (tid < 32) {
    float s = red[0][tid] + red[1][tid] + red[2][tid] + red[3][tid];
    rowsum[(size_t)b * N + nblk * 32 + tid] = s;
  }
}

// ---------------- rinv fold: vbf[b][c(48)][n] = bf16(v * 1/rowsum[n]) ------
__global__ __launch_bounds__(256) void vscale_kernel(
    const float* __restrict__ v, const float* __restrict__ rowsum,
    unsigned short* __restrict__ vbf) {
  int gid = blockIdx.x * 256 + threadIdx.x;  // = b*N + n
  int b = gid >> 12;
  int n = gid & (N - 1);
  float r = 1.0f / rowsum[gid];
#pragma unroll
  for (int c = 0; c < CQ; ++c)
    vbf[((size_t)b * CP + c) * N + n] = f2bf(v[((size_t)b * CQ + c) * N + n] * r);
#pragma unroll
  for (int c = CQ; c < CP; ++c) vbf[((size_t)b * CP + c) * N + n] = 0;
}

// ---------------- Pass 2: attn[c][m] += V'[c][n] * exp(s[n,m]) -------------
__global__ __launch_bounds__(256) void attn_kernel(
    const unsigned short* __restrict__ qT, const unsigned short* __restrict__ kT,
    const unsigned short* __restrict__ vbf, float* __restrict__ pattn) {
  __shared__ unsigned short plds[4][32 * 40];   // per-wave P^T tile [m][n pad40]
  int tid = threadIdx.x, lane = tid & 63, wave = tid >> 6;
  int b = blockIdx.y, z = blockIdx.z, mblk = blockIdx.x;
  int l31 = lane & 31, h = lane >> 5, l15 = lane & 15, q4 = lane >> 4;
  int m0 = mblk * 128 + wave * 32;
  // Q B-frags (loop-invariant): B[c = 8h+i+16mf][m = l31]
  const unsigned short* qrow = qT + ((size_t)b * N + m0 + l31) * CP + h * 8;
  bf8_t qb0 = *(const bf8_t*)(qrow);
  bf8_t qb1 = *(const bf8_t*)(qrow + 16);
  bf8_t qb2 = *(const bf8_t*)(qrow + 32);
  f32x4 acc[3][2];
#pragma unroll
  for (int ct = 0; ct < 3; ++ct)
#pragma unroll
    for (int hm = 0; hm < 2; ++hm)
#pragma unroll
      for (int r = 0; r < 4; ++r) acc[ct][hm][r] = 0.f;
  unsigned short* pl = plds[wave];
  const unsigned short* kbase = kT + ((size_t)b * N + z * NCHUNK + l31) * CP + h * 8;
  const unsigned short* vbase = vbf + (size_t)b * CP * N + z * NCHUNK + q4 * 8;
  for (int t = 0; t < NCHUNK / 32; ++t) {
    const unsigned short* krow = kbase + (size_t)t * 32 * CP;
    bf8_t a0 = *(const bf8_t*)(krow);
    bf8_t a1 = *(const bf8_t*)(krow + 16);
    bf8_t a2 = *(const bf8_t*)(krow + 32);
    f32x16 S;
#pragma unroll
    for (int r = 0; r < 16; ++r) S[r] = 0.f;
    S = __builtin_amdgcn_mfma_f32_32x32x16_bf16(a0, qb0, S, 0, 0, 0);
    S = __builtin_amdgcn_mfma_f32_32x32x16_bf16(a1, qb1, S, 0, 0, 0);
    S = __builtin_amdgcn_mfma_f32_32x32x16_bf16(a2, qb2, S, 0, 0, 0);
    // P = exp(S) -> bf16, store transposed [m][n] (rows 8qd+4h+0..3 contiguous)
#pragma unroll
    for (int qd = 0; qd < 4; ++qd) {
      unsigned short p0 = f2bf(__expf(S[4 * qd + 0]));
      unsigned short p1 = f2bf(__expf(S[4 * qd + 1]));
      unsigned short p2 = f2bf(__expf(S[4 * qd + 2]));
      unsigned short p3 = f2bf(__expf(S[4 * qd + 3]));
      uint2 pk;
      pk.x = (unsigned)p0 | ((unsigned)p1 << 16);
      pk.y = (unsigned)p2 | ((unsigned)p3 << 16);
      *(uint2*)&pl[l31 * 40 + 8 * qd + 4 * h] = pk;
    }
    // B-frags for PV: B[n = q4*8+i][m = l15] from plds[m][n] (in-wave DS order)
    bf8_t pb0 = *(const bf8_t*)&pl[l15 * 40 + q4 * 8];
    bf8_t pb1 = *(const bf8_t*)&pl[(16 + l15) * 40 + q4 * 8];
    // V A-frags: A[c = ct*16+l15][n = q4*8+i]
    const unsigned short* vrow = vbase + (size_t)t * 32;
    bf8_t v0 = *(const bf8_t*)(vrow + (size_t)(0 * 16 + l15) * N);
    bf8_t v1 = *(const bf8_t*)(vrow + (size_t)(1 * 16 + l15) * N);
    bf8_t v2 = *(const bf8_t*)(vrow + (size_t)(2 * 16 + l15) * N);
    acc[0][0] = __builtin_amdgcn_mfma_f32_16x16x32_bf16(v0, pb0, acc[0][0], 0, 0, 0);
    acc[0][1] = __builtin_amdgcn_mfma_f32_16x16x32_bf16(v0, pb1, acc[0][1], 0, 0, 0);
    acc[1][0] = __builtin_amdgcn_mfma_f32_16x16x32_bf16(v1, pb0, acc[1][0], 0, 0, 0);
    acc[1][1] = __builtin_amdgcn_mfma_f32_16x16x32_bf16(v1, pb1, acc[1][1], 0, 0, 0);
    acc[2][0] = __builtin_amdgcn_mfma_f32_16x16x32_bf16(v2, pb0, acc[2][0], 0, 0, 0);
    acc[2][1] = __builtin_amdgcn_mfma_f32_16x16x32_bf16(v2, pb1, acc[2][1], 0, 0, 0);
  }
  // epilogue: D col = l15, row = q4*4 + reg (16x16 C/D map)
#pragma unroll
  for (int ct = 0; ct < 3; ++ct)
#pragma unroll
    for (int hm = 0; hm < 2; ++hm)
#pragma unroll
      for (int r = 0; r < 4; ++r) {
        int c = ct * 16 + q4 * 4 + r;
        if (c < CQ)
          pattn[(((size_t)z * B + b) * CQ + c) * N + m0 + hm * 16 + l15] = acc[ct][hm][r];
      }
}

// ---------------- sum z-splits + output projection -------------------------
__global__ __launch_bounds__(256) void out_kernel(
    const float* __restrict__ pattn,
    const float* __restrict__ wo, const float* __restrict__ bo,
    float* __restrict__ out) {
  __shared__ float swo[CIN * CQ];
  __shared__ float sbo[CIN];
  int tid = threadIdx.x;
  for (int e = tid; e < CIN * CQ; e += 256) swo[e] = wo[e];
  if (tid < CIN) sbo[tid] = bo[tid];
  __syncthreads();
  int gid = blockIdx.x * 256 + tid;
  int b = gid >> 12;
  int m = gid & (N - 1);
  float at[CQ];
#pragma unroll
  for (int c = 0; c < CQ; ++c) {
    float s = 0.f;
#pragma unroll
    for (int z = 0; z < ZSPLIT; ++z)
      s += pattn[(((size_t)z * B + b) * CQ + c) * N + m];
    at[c] = s;
  }
#pragma unroll
  for (int i = 0; i < CIN; ++i) {
    float o = sbo[i];
#pragma unroll
    for (int c = 0; c < CQ; ++c) o += swo[i * CQ + c] * at[c];
    out[(b * CIN + i) * N + m] = o;
  }
}

extern "C" void kernel_launch(void* const* d_in, const int* in_sizes, int n_in,
                              void* d_out, int out_size, void* d_ws, size_t ws_size,
                              hipStream_t stream) {
  const float* x  = (const float*)d_in[0];
  const float* wq = (const float*)d_in[1];
  const float* bq = (const float*)d_in[2];
  const float* wk = (const float*)d_in[3];
  const float* bk = (const float*)d_in[4];
  const float* wv = (const float*)d_in[5];
  const float* bv = (const float*)d_in[6];
  const float* wo = (const float*)d_in[7];
  const float* bo = (const float*)d_in[8];
  float* out = (float*)d_out;

  char* ws = (char*)d_ws;
  unsigned short* qT  = (unsigned short*)ws;                        // 3,145,728 B
  unsigned short* kT  = (unsigned short*)(ws + 3145728);            // 3,145,728 B
  unsigned short* vbf = (unsigned short*)(ws + 2 * 3145728);        // 3,145,728 B
  float* v      = (float*)(ws + 3 * 3145728);                       // 4,718,592 B
  float* rowsum = (float*)(ws + 3 * 3145728 + 4718592);             //   131,072 B
  float* pattn  = (float*)(ws + 3 * 3145728 + 4718592 + 131072);    // 18,874,368 B

  qkv_kernel<<<B * N / 256, 256, 0, stream>>>(x, wq, bq, wk, bk, wv, bv, qT, kT, v);
  stats_kernel<<<dim3(N / 32, B), 256, 0, stream>>>(qT, kT, rowsum);
  vscale_kernel<<<B * N / 256, 256, 0, stream>>>(v, rowsum, vbf);
  attn_kernel<<<dim3(N / 128, B, ZSPLIT), 256, 0, stream>>>(qT, kT, vbf, pattn);
  out_kernel<<<B * N / 256, 256, 0, stream>>>(pattn, wo, bo, out);
}

// Round 3
// 185.211 us; speedup vs baseline: 3.7735x; 1.2102x over previous
//
#include <hip/hip_runtime.h>
#include <hip/hip_bf16.h>

#define B 8
#define CIN 12
#define CQ 36
#define CP 48               // channel dim padded for MFMA K (3x16)
#define N 4096
#define SCALE 0.28867513459481287f   // 1/sqrt(12)
#define ZSPLIT 8
#define NCHUNK (N / ZSPLIT) // 512
#define MSPLIT 2

typedef __attribute__((ext_vector_type(8)))  short bf8_t;   // 8 bf16 = 4 VGPRs
typedef __attribute__((ext_vector_type(16))) float f32x16;
typedef __attribute__((ext_vector_type(4)))  float f32x4;

__device__ __forceinline__ unsigned short f2bf(float x) {
  unsigned int u = __float_as_uint(x);
  u += 0x7FFFu + ((u >> 16) & 1u);   // round-to-nearest-even
  return (unsigned short)(u >> 16);
}

#if __has_builtin(__builtin_amdgcn_cvt_pk_bf16_f32)
typedef __attribute__((ext_vector_type(2))) __bf16 bf16x2_t;
__device__ __forceinline__ unsigned pk2bf(float a, float b) {
  bf16x2_t v = __builtin_amdgcn_cvt_pk_bf16_f32(a, b);
  return __builtin_bit_cast(unsigned, v);
}
#else
__device__ __forceinline__ unsigned pk2bf(float a, float b) {
  return (unsigned)f2bf(a) | ((unsigned)f2bf(b) << 16);
}
#endif

__device__ __forceinline__ float bf2f(unsigned short u) {
  return __uint_as_float((unsigned)u << 16);
}

// ---------------- QKV projection: y-split over {q,k,v} ---------------------
__global__ __launch_bounds__(256) void qkv_kernel(
    const float* __restrict__ x,
    const float* __restrict__ wq, const float* __restrict__ bq,
    const float* __restrict__ wk, const float* __restrict__ bk,
    const float* __restrict__ wv, const float* __restrict__ bv,
    unsigned short* __restrict__ qT, unsigned short* __restrict__ kT,
    float* __restrict__ v) {
  __shared__ float sw[CQ * CIN];
  __shared__ float sb[CQ];
  int z = blockIdx.y;   // 0->q, 1->k (scaled), 2->v
  const float* w  = (z == 0) ? wq : (z == 1) ? wk : wv;
  const float* bb = (z == 0) ? bq : (z == 1) ? bk : bv;
  float scale = (z == 1) ? SCALE : 1.0f;
  int tid = threadIdx.x;
  for (int e = tid; e < CQ * CIN; e += 256) sw[e] = w[e] * scale;
  if (tid < CQ) sb[tid] = bb[tid] * scale;
  __syncthreads();
  int gid = blockIdx.x * 256 + tid;    // over B*N
  int b = gid >> 12;
  int n = gid & (N - 1);
  float xv[CIN];
#pragma unroll
  for (int i = 0; i < CIN; ++i) xv[i] = x[(b * CIN + i) * N + n];
  if (z == 2) {
#pragma unroll
    for (int o = 0; o < CQ; ++o) {
      float a = sb[o];
#pragma unroll
      for (int i = 0; i < CIN; ++i) a += sw[o * CIN + i] * xv[i];
      v[((size_t)b * CQ + o) * N + n] = a;
    }
  } else {
    __attribute__((aligned(16))) unsigned row[CP / 2];
#pragma unroll
    for (int o = 0; o < CQ; o += 2) {
      float a0 = sb[o], a1 = sb[o + 1];
#pragma unroll
      for (int i = 0; i < CIN; ++i) {
        float xi = xv[i];
        a0 += sw[o * CIN + i] * xi;
        a1 += sw[(o + 1) * CIN + i] * xi;
      }
      row[o / 2] = pk2bf(a0, a1);
    }
#pragma unroll
    for (int o = CQ / 2; o < CP / 2; ++o) row[o] = 0;
    unsigned short* dst = ((z == 0) ? qT : kT) + ((size_t)b * N + n) * CP;
#pragma unroll
    for (int i = 0; i < 6; ++i) *(uint4*)(dst + 8 * i) = *(const uint4*)&row[4 * i];
  }
}

// ---------------- Pass 1: psum[z][b][n] = partial sum_m exp(s[n,m]) --------
__global__ __launch_bounds__(256) void stats_kernel(
    const unsigned short* __restrict__ qT, const unsigned short* __restrict__ kT,
    float* __restrict__ psum) {
  __shared__ float red[4][32];
  int tid = threadIdx.x, lane = tid & 63, wave = tid >> 6;
  int b = blockIdx.y, nblk = blockIdx.x, z = blockIdx.z;
  int l31 = lane & 31, h = lane >> 5;
  const unsigned short* krow = kT + ((size_t)b * N + nblk * 32 + l31) * CP + h * 8;
  bf8_t a0 = *(const bf8_t*)(krow);
  bf8_t a1 = *(const bf8_t*)(krow + 16);
  bf8_t a2 = *(const bf8_t*)(krow + 32);
  float rs[16];
#pragma unroll
  for (int r = 0; r < 16; ++r) rs[r] = 0.f;
  const int MW = N / MSPLIT / 4;   // 512 m per wave
  const unsigned short* qbase =
      qT + ((size_t)b * N + z * (N / MSPLIT) + wave * MW + l31) * CP + h * 8;
  for (int t = 0; t < MW / 32; ++t) {
    const unsigned short* qrow2 = qbase + (size_t)t * 32 * CP;
    bf8_t b0 = *(const bf8_t*)(qrow2);
    bf8_t b1 = *(const bf8_t*)(qrow2 + 16);
    bf8_t b2 = *(const bf8_t*)(qrow2 + 32);
    f32x16 S;
#pragma unroll
    for (int r = 0; r < 16; ++r) S[r] = 0.f;
    S = __builtin_amdgcn_mfma_f32_32x32x16_bf16(a0, b0, S, 0, 0, 0);
    S = __builtin_amdgcn_mfma_f32_32x32x16_bf16(a1, b1, S, 0, 0, 0);
    S = __builtin_amdgcn_mfma_f32_32x32x16_bf16(a2, b2, S, 0, 0, 0);
#pragma unroll
    for (int r = 0; r < 16; ++r) rs[r] += __expf(S[r]);
  }
#pragma unroll
  for (int off = 16; off >= 1; off >>= 1)
#pragma unroll
    for (int r = 0; r < 16; ++r) rs[r] += __shfl_xor(rs[r], off, 32);
  if (l31 == 0) {
#pragma unroll
    for (int r = 0; r < 16; ++r) {
      int row = (r & 3) + 8 * (r >> 2) + 4 * h;   // 32x32 C/D row map
      red[wave][row] = rs[r];
    }
  }
  __syncthreads();
  if (tid < 32) {
    float s = red[0][tid] + red[1][tid] + red[2][tid] + red[3][tid];
    psum[((size_t)z * B + b) * N + nblk * 32 + tid] = s;
  }
}

// ---------------- vbf[b][c][n] = bf16(v * 1/rowsum[n]) (c-split) -----------
__global__ __launch_bounds__(256) void vscale_kernel(
    const float* __restrict__ v, const float* __restrict__ psum,
    unsigned short* __restrict__ vbf) {
  int gid = blockIdx.x * 256 + threadIdx.x;  // = b*N + n
  int b = gid >> 12;
  int n = gid & (N - 1);
  float r = 1.0f / (psum[gid] + psum[(size_t)B * N + gid]);
  int c0 = blockIdx.y * 12;
#pragma unroll
  for (int j = 0; j < 12; ++j) {
    int c = c0 + j;
    vbf[((size_t)b * CP + c) * N + n] = f2bf(v[((size_t)b * CQ + c) * N + n] * r);
  }
  // vbf rows 36..47 left unwritten: MFMA output rows are independent, those
  // A-rows only feed unstored output channels.
}

// ---------------- Pass 2: pattn[z][c][m] (bf16) ----------------------------
__global__ __launch_bounds__(256) void attn_kernel(
    const unsigned short* __restrict__ qT, const unsigned short* __restrict__ kT,
    const unsigned short* __restrict__ vbf, unsigned short* __restrict__ pattn) {
  __shared__ unsigned short plds[4][32 * 40];   // per-wave P^T tile [m][n pad40]
  int tid = threadIdx.x, lane = tid & 63, wave = tid >> 6;
  int b = blockIdx.y, z = blockIdx.z, mblk = blockIdx.x;
  int l31 = lane & 31, h = lane >> 5, l15 = lane & 15, q4 = lane >> 4;
  int m0 = mblk * 128 + wave * 32;
  const unsigned short* qrow = qT + ((size_t)b * N + m0 + l31) * CP + h * 8;
  bf8_t qb0 = *(const bf8_t*)(qrow);
  bf8_t qb1 = *(const bf8_t*)(qrow + 16);
  bf8_t qb2 = *(const bf8_t*)(qrow + 32);
  f32x4 acc[3][2];
#pragma unroll
  for (int ct = 0; ct < 3; ++ct)
#pragma unroll
    for (int hm = 0; hm < 2; ++hm)
#pragma unroll
      for (int r = 0; r < 4; ++r) acc[ct][hm][r] = 0.f;
  unsigned short* pl = plds[wave];
  const unsigned short* kbase = kT + ((size_t)b * N + z * NCHUNK + l31) * CP + h * 8;
  const unsigned short* vbase = vbf + (size_t)b * CP * N + z * NCHUNK + q4 * 8;
  for (int t = 0; t < NCHUNK / 32; ++t) {
    const unsigned short* krow = kbase + (size_t)t * 32 * CP;
    bf8_t a0 = *(const bf8_t*)(krow);
    bf8_t a1 = *(const bf8_t*)(krow + 16);
    bf8_t a2 = *(const bf8_t*)(krow + 32);
    f32x16 S;
#pragma unroll
    for (int r = 0; r < 16; ++r) S[r] = 0.f;
    S = __builtin_amdgcn_mfma_f32_32x32x16_bf16(a0, qb0, S, 0, 0, 0);
    S = __builtin_amdgcn_mfma_f32_32x32x16_bf16(a1, qb1, S, 0, 0, 0);
    S = __builtin_amdgcn_mfma_f32_32x32x16_bf16(a2, qb2, S, 0, 0, 0);
#pragma unroll
    for (int qd = 0; qd < 4; ++qd) {
      uint2 pk;
      pk.x = pk2bf(__expf(S[4 * qd + 0]), __expf(S[4 * qd + 1]));
      pk.y = pk2bf(__expf(S[4 * qd + 2]), __expf(S[4 * qd + 3]));
      *(uint2*)&pl[l31 * 40 + 8 * qd + 4 * h] = pk;
    }
    bf8_t pb0 = *(const bf8_t*)&pl[l15 * 40 + q4 * 8];
    bf8_t pb1 = *(const bf8_t*)&pl[(16 + l15) * 40 + q4 * 8];
    const unsigned short* vrow = vbase + (size_t)t * 32;
    bf8_t v0 = *(const bf8_t*)(vrow + (size_t)(0 * 16 + l15) * N);
    bf8_t v1 = *(const bf8_t*)(vrow + (size_t)(1 * 16 + l15) * N);
    bf8_t v2 = *(const bf8_t*)(vrow + (size_t)(2 * 16 + l15) * N);
    acc[0][0] = __builtin_amdgcn_mfma_f32_16x16x32_bf16(v0, pb0, acc[0][0], 0, 0, 0);
    acc[0][1] = __builtin_amdgcn_mfma_f32_16x16x32_bf16(v0, pb1, acc[0][1], 0, 0, 0);
    acc[1][0] = __builtin_amdgcn_mfma_f32_16x16x32_bf16(v1, pb0, acc[1][0], 0, 0, 0);
    acc[1][1] = __builtin_amdgcn_mfma_f32_16x16x32_bf16(v1, pb1, acc[1][1], 0, 0, 0);
    acc[2][0] = __builtin_amdgcn_mfma_f32_16x16x32_bf16(v2, pb0, acc[2][0], 0, 0, 0);
    acc[2][1] = __builtin_amdgcn_mfma_f32_16x16x32_bf16(v2, pb1, acc[2][1], 0, 0, 0);
  }
#pragma unroll
  for (int ct = 0; ct < 3; ++ct)
#pragma unroll
    for (int hm = 0; hm < 2; ++hm)
#pragma unroll
      for (int r = 0; r < 4; ++r) {
        int c = ct * 16 + q4 * 4 + r;
        if (c < CQ)
          pattn[(((size_t)z * B + b) * CQ + c) * N + m0 + hm * 16 + l15] =
              f2bf(acc[ct][hm][r]);
      }
}

// ---------------- zero d_out (poisoned 0xAA by harness) --------------------
__global__ __launch_bounds__(256) void zero_kernel(float4* __restrict__ p) {
  p[blockIdx.x * 256 + threadIdx.x] = float4{0.f, 0.f, 0.f, 0.f};
}

// ---------------- sum z-splits + output projection (c-split x2) ------------
__global__ __launch_bounds__(256) void out_kernel(
    const unsigned short* __restrict__ pattn,
    const float* __restrict__ wo, const float* __restrict__ bo,
    float* __restrict__ out) {
  __shared__ float swo[CIN * CQ];
  __shared__ float sbo[CIN];
  int tid = threadIdx.x;
  for (int e = tid; e < CIN * CQ; e += 256) swo[e] = wo[e];
  if (tid < CIN) sbo[tid] = bo[tid];
  __syncthreads();
  int half = blockIdx.y;            // c in [half*18, half*18+18)
  int gid = blockIdx.x * 256 + tid;
  int b = gid >> 12;
  int m = gid & (N - 1);
  float at[18];
#pragma unroll
  for (int j = 0; j < 18; ++j) {
    int c = half * 18 + j;
    float s = 0.f;
#pragma unroll
    for (int z = 0; z < ZSPLIT; ++z)
      s += bf2f(pattn[(((size_t)z * B + b) * CQ + c) * N + m]);
    at[j] = s;
  }
#pragma unroll
  for (int i = 0; i < CIN; ++i) {
    float o = (half == 0) ? sbo[i] : 0.f;
#pragma unroll
    for (int j = 0; j < 18; ++j) o += swo[i * CQ + half * 18 + j] * at[j];
    atomicAdd(&out[((size_t)b * CIN + i) * N + m], o);
  }
}

extern "C" void kernel_launch(void* const* d_in, const int* in_sizes, int n_in,
                              void* d_out, int out_size, void* d_ws, size_t ws_size,
                              hipStream_t stream) {
  const float* x  = (const float*)d_in[0];
  const float* wq = (const float*)d_in[1];
  const float* bq = (const float*)d_in[2];
  const float* wk = (const float*)d_in[3];
  const float* bk = (const float*)d_in[4];
  const float* wv = (const float*)d_in[5];
  const float* bv = (const float*)d_in[6];
  const float* wo = (const float*)d_in[7];
  const float* bo = (const float*)d_in[8];
  float* out = (float*)d_out;

  char* ws = (char*)d_ws;
  unsigned short* qT  = (unsigned short*)ws;                        // 3,145,728 B
  unsigned short* kT  = (unsigned short*)(ws + 3145728);            // 3,145,728 B
  unsigned short* vbf = (unsigned short*)(ws + 2 * 3145728);        // 3,145,728 B
  float* v    = (float*)(ws + 3 * 3145728);                         // 4,718,592 B
  float* psum = (float*)(ws + 3 * 3145728 + 4718592);               //   262,144 B
  unsigned short* pattn =
      (unsigned short*)(ws + 3 * 3145728 + 4718592 + 262144);       // 18,874,368 B

  qkv_kernel<<<dim3(B * N / 256, 3), 256, 0, stream>>>(x, wq, bq, wk, bk, wv, bv,
                                                       qT, kT, v);
  stats_kernel<<<dim3(N / 32, B, MSPLIT), 256, 0, stream>>>(qT, kT, psum);
  vscale_kernel<<<dim3(B * N / 256, 3), 256, 0, stream>>>(v, psum, vbf);
  attn_kernel<<<dim3(N / 128, B, ZSPLIT), 256, 0, stream>>>(qT, kT, vbf, pattn);
  zero_kernel<<<B * CIN * N / 1024, 256, 0, stream>>>((float4*)out);
  out_kernel<<<dim3(B * N / 256, 2), 256, 0, stream>>>(pattn, wo, bo, out);
}